// Round 1
// baseline (212.473 us; speedup 1.0000x reference)
//
#include <hip/hip_runtime.h>
#include <cstdint>

#define BATCHES 8
#define NPTS 2048
#define NF 512
#define KNN 32
#define WAVES 4   // waves per block
#define QPW 4     // queries per wave; block covers WAVES*QPW = 16 queries

// grid = BATCHES * (NPTS / 16) = 8 * 128 = 1024 blocks
// batch = blockIdx.x & 7  -> XCD-affinity swizzle so each XCD's L2 holds one
// batch's 4 MB feature matrix during the gather phase.

__global__ __launch_bounds__(256, 4)
void pointnetpp_knn_maxpool(const float* __restrict__ x,
                            const float* __restrict__ points,
                            float* __restrict__ out) {
    __shared__ float pts[NPTS * 3];          // 24 KiB, interleaved [N][3]
    __shared__ int   sel[WAVES][KNN];

    const int tid  = threadIdx.x;
    const int lane = tid & 63;
    const int w    = tid >> 6;

    const int b     = blockIdx.x & 7;        // batch (XCD affinity)
    const int chunk = blockIdx.x >> 3;       // 0..127 query chunk

    // ---- stage points[b] into LDS (coalesced float4 copy) ----
    {
        const float4* src = (const float4*)(points + (size_t)b * NPTS * 3);
        float4*       dst = (float4*)pts;
        #pragma unroll
        for (int k = 0; k < (NPTS * 3 / 4) / 256; ++k)   // 6 iters
            dst[tid + k * 256] = src[tid + k * 256];
    }
    __syncthreads();

    const uint64_t lmlt = (1ull << lane) - 1ull;   // lanes below me
    const float*   xb   = x + (size_t)b * NPTS * NF;

    for (int q = 0; q < QPW; ++q) {
        const int i = chunk * (WAVES * QPW) + w * QPW + q;   // query index

        const float qx = pts[i * 3 + 0];   // LDS broadcast (same addr all lanes)
        const float qy = pts[i * 3 + 1];
        const float qz = pts[i * 3 + 2];

        // ---- squared distances, candidates n = lane + 64*j ----
        uint32_t db[32];
        #pragma unroll
        for (int j = 0; j < 32; ++j) {
            const int n = lane + (j << 6);
            const float dx = qx - pts[n * 3 + 0];
            const float dy = qy - pts[n * 3 + 1];
            const float dz = qz - pts[n * 3 + 2];
            const float d2 = dx * dx + dy * dy + dz * dz;
            db[j] = __float_as_uint(d2);     // d2 >= 0: bit pattern is monotone
        }

        // ---- binary search on bit patterns for T = 32nd smallest value ----
        // invariant: count(<= lo) < KNN, count(<= hi) >= KNN
        uint32_t lo = 0u, hi = 0x7F800000u;  // count(<=0)=1 (self), count(<=inf)=N
        while (hi - lo > 1u) {
            const uint32_t mid = lo + ((hi - lo) >> 1);
            uint32_t c = 0;
            #pragma unroll
            for (int j = 0; j < 32; ++j) c += (db[j] <= mid) ? 1u : 0u;
            #pragma unroll
            for (int m = 1; m < 64; m <<= 1) c += (uint32_t)__shfl_xor((int)c, m);
            const uint32_t cs = __builtin_amdgcn_readfirstlane(c);
            if (cs >= KNN) hi = mid; else lo = mid;
        }
        const uint32_t T = hi;

        // ---- count strictly-less (wave-uniform) ----
        uint32_t cl = 0;
        #pragma unroll
        for (int j = 0; j < 32; ++j) cl += (db[j] < T) ? 1u : 0u;
        #pragma unroll
        for (int m = 1; m < 64; m <<= 1) cl += (uint32_t)__shfl_xor((int)cl, m);
        const int cnt_lt = __builtin_amdgcn_readfirstlane(cl);   // < KNN

        // ---- emit exactly KNN indices: all strict-less, then ties fill ----
        int base_lt = 0, base_eq = 0;
        #pragma unroll
        for (int j = 0; j < 32; ++j) {
            const bool lt = db[j] < T;
            const bool eq = db[j] == T;
            const uint64_t mlt = __ballot(lt);
            const uint64_t meq = __ballot(eq);
            int slot = -1;
            if (lt) {
                slot = base_lt + (int)__popcll(mlt & lmlt);
            } else if (eq) {
                const int s = cnt_lt + base_eq + (int)__popcll(meq & lmlt);
                if (s < KNN) slot = s;
            }
            if (slot >= 0) sel[w][slot] = lane + (j << 6);
            base_lt += (int)__popcll(mlt);
            base_eq += (int)__popcll(meq);
        }
        // same-wave LDS RAW: compiler inserts lgkmcnt wait; no barrier needed

        // ---- gather + max-pool: 32 rows x 512 floats, float4 coalesced ----
        float4 a0 = make_float4(-INFINITY, -INFINITY, -INFINITY, -INFINITY);
        float4 a1 = a0;
        #pragma unroll 4
        for (int k = 0; k < KNN; ++k) {
            const int nb = sel[w][k];
            const float4* row = (const float4*)(xb + (size_t)nb * NF);
            const float4 v0 = row[lane];
            const float4 v1 = row[lane + 64];
            a0.x = fmaxf(a0.x, v0.x);  a0.y = fmaxf(a0.y, v0.y);
            a0.z = fmaxf(a0.z, v0.z);  a0.w = fmaxf(a0.w, v0.w);
            a1.x = fmaxf(a1.x, v1.x);  a1.y = fmaxf(a1.y, v1.y);
            a1.z = fmaxf(a1.z, v1.z);  a1.w = fmaxf(a1.w, v1.w);
        }

        float4* orow = (float4*)(out + ((size_t)b * NPTS + i) * NF);
        orow[lane]      = a0;
        orow[lane + 64] = a1;
    }
}

extern "C" void kernel_launch(void* const* d_in, const int* in_sizes, int n_in,
                              void* d_out, int out_size, void* d_ws, size_t ws_size,
                              hipStream_t stream) {
    const float* x      = (const float*)d_in[0];   // [8, 2048, 512] f32
    const float* points = (const float*)d_in[1];   // [8, 2048, 3]   f32
    float* out          = (float*)d_out;           // [8, 2048, 512] f32

    pointnetpp_knn_maxpool<<<dim3(BATCHES * (NPTS / (WAVES * QPW))),
                             dim3(256), 0, stream>>>(x, points, out);
}

// Round 3
// 179.392 us; speedup vs baseline: 1.1844x; 1.1844x over previous
//
#include <hip/hip_runtime.h>
#include <cstdint>

#define BATCHES 8
#define NPTS 2048
#define NF 512
#define KNN 32
#define WAVES 4   // waves per block
#define QPW 4     // queries per wave; block covers 16 queries

// grid = 8 batches * 128 chunks = 1024 blocks; batch = blockIdx & 7 (XCD L2 affinity)

__global__ __launch_bounds__(256, 4)
void pointnetpp_knn_maxpool(const float* __restrict__ x,
                            const float* __restrict__ points,
                            float* __restrict__ out) {
    __shared__ __align__(16) float        pts[NPTS * 3];     // 24 KiB
    __shared__ __align__(16) unsigned int hist[WAVES][256];  // 4 KiB
    __shared__ __align__(16) int          sel[WAVES][KNN];   // 512 B

    const int tid  = threadIdx.x;
    const int lane = tid & 63;
    const int w    = tid >> 6;

    const int b     = blockIdx.x & 7;
    const int chunk = blockIdx.x >> 3;

    // ---- stage points[b] into LDS ----
    {
        const float4* src = (const float4*)(points + (size_t)b * NPTS * 3);
        float4*       dst = (float4*)pts;
        #pragma unroll
        for (int k = 0; k < (NPTS * 3 / 4) / 256; ++k)
            dst[tid + k * 256] = src[tid + k * 256];
    }
    __syncthreads();

    const uint64_t lmlt = (1ull << lane) - 1ull;
    const float*   xb   = x + (size_t)b * NPTS * NF;

    for (int q = 0; q < QPW; ++q) {
        const int i = chunk * (WAVES * QPW) + w * QPW + q;

        const float qx = pts[i * 3 + 0];
        const float qy = pts[i * 3 + 1];
        const float qz = pts[i * 3 + 2];

        // ---- squared distances (bit patterns; d2>=0 so order-isomorphic) ----
        uint32_t db[32];
        #pragma unroll
        for (int j = 0; j < 32; ++j) {
            const int n = lane + (j << 6);
            const float dx = qx - pts[n * 3 + 0];
            const float dy = qy - pts[n * 3 + 1];
            const float dz = qz - pts[n * 3 + 2];
            const float d2 = dx * dx + dy * dy + dz * dz;
            db[j] = __float_as_uint(d2);
        }

        // ---- exact 4-pass radix select: T = 32nd smallest, base = count(<T) ----
        uint32_t prefix = 0, base = 0, need = KNN;
        const int shv[4] = {23, 15, 7, 0};
        const int wdv[4] = {8, 8, 8, 7};
        #pragma unroll
        for (int p = 0; p < 4; ++p) {
            const int      sh   = shv[p];
            const int      wd   = wdv[p];
            const uint32_t dmsk = (1u << wd) - 1u;

            // zero my 4 bins (16B-aligned by declaration)
            ((uint4*)hist[w])[lane] = make_uint4(0u, 0u, 0u, 0u);

            // predicated histogram: only matching values touch LDS
            #pragma unroll
            for (int j = 0; j < 32; ++j) {
                const uint32_t v = db[j];
                if ((v >> (sh + wd)) == prefix)
                    atomicAdd(&hist[w][(v >> sh) & dmsk], 1u);
            }

            // read 4 contiguous bins; exclusive scan of lane sums across wave
            const uint4 h = ((const uint4*)hist[w])[lane];
            const uint32_t lsum = h.x + h.y + h.z + h.w;
            uint32_t incl = lsum;
            #pragma unroll
            for (int m = 1; m < 64; m <<= 1) {
                const uint32_t t = (uint32_t)__shfl_up((int)incl, m);
                if (lane >= m) incl += t;
            }
            const uint32_t c0 = incl - lsum;
            const uint32_t c1 = c0 + h.x;
            const uint32_t c2 = c1 + h.y;
            const uint32_t c3 = c2 + h.z;

            // pack winning (bin, cumExcl) and min-reduce via shuffles
            int cand = 0x7FFFFFFF;   // ce <= 2047 fits 12 bits; bin <= 255
            if (c0 < need && need <= c0 + h.x) cand = (int)(((uint32_t)(lane*4+0) << 12) | c0);
            if (c1 < need && need <= c1 + h.y) cand = (int)(((uint32_t)(lane*4+1) << 12) | c1);
            if (c2 < need && need <= c2 + h.z) cand = (int)(((uint32_t)(lane*4+2) << 12) | c2);
            if (c3 < need && need <= c3 + h.w) cand = (int)(((uint32_t)(lane*4+3) << 12) | c3);
            #pragma unroll
            for (int m = 1; m < 64; m <<= 1)
                cand = min(cand, __shfl_xor(cand, m));

            const uint32_t B  = ((uint32_t)cand) >> 12;
            const uint32_t ce = ((uint32_t)cand) & 0xFFFu;
            prefix = (prefix << wd) | B;
            need  -= ce;
            base  += ce;
        }
        const uint32_t T      = prefix;
        const int      cnt_lt = (int)base;

        // ---- emit exactly KNN indices: strict-less first, then ties in n-order ----
        int base_lt = 0, base_eq = 0;
        #pragma unroll
        for (int j = 0; j < 32; ++j) {
            const bool lt = db[j] < T;
            const bool eq = db[j] == T;
            const uint64_t mlt = __ballot(lt);
            const uint64_t meq = __ballot(eq);
            int slot = -1;
            if (lt) {
                slot = base_lt + (int)__popcll(mlt & lmlt);
            } else if (eq) {
                slot = cnt_lt + base_eq + (int)__popcll(meq & lmlt);
            }
            if (slot >= 0 && slot < KNN) sel[w][slot] = lane + (j << 6);
            base_lt += (int)__popcll(mlt);
            base_eq += (int)__popcll(meq);
        }

        // ---- gather + max-pool: 32 rows x 512 f32, float4 coalesced ----
        float4 a0 = make_float4(-INFINITY, -INFINITY, -INFINITY, -INFINITY);
        float4 a1 = a0;
        #pragma unroll 4
        for (int k = 0; k < KNN; ++k) {
            const int nb = sel[w][k] & (NPTS - 1);   // clamp: bug => absmax, not fault
            const float4* row = (const float4*)(xb + (size_t)nb * NF);
            const float4 v0 = row[lane];
            const float4 v1 = row[lane + 64];
            a0.x = fmaxf(a0.x, v0.x);  a0.y = fmaxf(a0.y, v0.y);
            a0.z = fmaxf(a0.z, v0.z);  a0.w = fmaxf(a0.w, v0.w);
            a1.x = fmaxf(a1.x, v1.x);  a1.y = fmaxf(a1.y, v1.y);
            a1.z = fmaxf(a1.z, v1.z);  a1.w = fmaxf(a1.w, v1.w);
        }

        float4* orow = (float4*)(out + ((size_t)b * NPTS + i) * NF);
        orow[lane]      = a0;
        orow[lane + 64] = a1;
    }
}

extern "C" void kernel_launch(void* const* d_in, const int* in_sizes, int n_in,
                              void* d_out, int out_size, void* d_ws, size_t ws_size,
                              hipStream_t stream) {
    const float* x      = (const float*)d_in[0];   // [8, 2048, 512] f32
    const float* points = (const float*)d_in[1];   // [8, 2048, 3]   f32
    float* out          = (float*)d_out;           // [8, 2048, 512] f32

    pointnetpp_knn_maxpool<<<dim3(BATCHES * (NPTS / (WAVES * QPW))),
                             dim3(256), 0, stream>>>(x, points, out);
}